// Round 1
// baseline (238.218 us; speedup 1.0000x reference)
//
#include <hip/hip_runtime.h>
#include <math.h>

typedef __attribute__((ext_vector_type(8)))  short short8;   // 8 x bf16 (4 VGPR) MFMA operand
typedef __attribute__((ext_vector_type(16))) float float16;  // 32x32 MFMA accumulator

#define DEVI __device__ __forceinline__

DEVI short f2bf(float f) {                      // RNE float -> bf16 bits
    unsigned u = __float_as_uint(f);
    u = (u + 0x7fffu + ((u >> 16) & 1u)) >> 16;
    return (short)u;
}
DEVI unsigned pk2(float a, float b) {           // pack two bf16 (a = low/first)
    return (unsigned)(unsigned short)f2bf(a) | ((unsigned)(unsigned short)f2bf(b) << 16);
}
DEVI float16 mfma16(short8 a, short8 b, float16 c) {
    return __builtin_amdgcn_mfma_f32_32x32x16_bf16(a, b, c, 0, 0, 0);
}
// C/D row for reg r, half h: row = (r&3) + 8*(r>>2) + 4*h  [guide-verified]
DEVI int rowof(int r, int h) { return (r & 3) + 8 * (r >> 2) + 4 * h; }

// ---------------- prologue: fp32 [K][N] weights -> bf16 [N][Kpad] in ws -------
// regions (in shorts): W1t 0 (512x384), W2t 196608 (256x512), W3t 327680 (128x256),
//                      Wc1t 360448 (64x160), Wc2t 370688 (32x64); total 372736
__global__ void prep_weights(const float* __restrict__ W1, const float* __restrict__ W2,
                             const float* __restrict__ W3, const float* __restrict__ Wc1,
                             const float* __restrict__ Wc2, short* __restrict__ ws) {
    int idx = blockIdx.x * 256 + threadIdx.x;
    const float* src; int K, N, kpad, local, base;
    if (idx < 196608)      { base = 0;      local = idx;          K = 365; N = 512; kpad = 384; src = W1;  }
    else if (idx < 327680) { base = 196608; local = idx - 196608; K = 512; N = 256; kpad = 512; src = W2;  }
    else if (idx < 360448) { base = 327680; local = idx - 327680; K = 256; N = 128; kpad = 256; src = W3;  }
    else if (idx < 370688) { base = 360448; local = idx - 360448; K = 160; N = 64;  kpad = 160; src = Wc1; }
    else                   { base = 370688; local = idx - 370688; K = 64;  N = 32;  kpad = 64;  src = Wc2; }
    int n = local / kpad, kp = local - n * kpad;
    float v = (kp < K) ? src[kp * N + n] : 0.0f;
    ws[base + local] = f2bf(v);
}

// ---------------- fused main kernel: 512 blocks x 512 threads, BM=128 ---------
__global__ __launch_bounds__(512, 2)
void fused_mlp(const float* __restrict__ x,
               const float* __restrict__ b1f, const float* __restrict__ b2f,
               const float* __restrict__ b3f, const float* __restrict__ Wsf,
               const float* __restrict__ bsf, const float* __restrict__ bc1f,
               const float* __restrict__ bc2f, const float* __restrict__ Wc3f,
               const float* __restrict__ bc3f,
               const short* __restrict__ W1t, const short* __restrict__ W2t,
               const short* __restrict__ W3t, const short* __restrict__ Wc1t,
               const short* __restrict__ Wc2t, float* __restrict__ out)
{
    __shared__ __align__(16) char smem[63488];
    short* AB0  = (short*)(smem);           // G1 A double-buffer, [128][32] swizzled, 8192 B each
    short* AB1  = (short*)(smem + 8192);
    short* SB0  = (short*)(smem + 16384);   // staging [128][72] bf16, 18432 B each
    short* SB1  = (short*)(smem + 34816);
    short* C1s  = (short*)(smem + 16384);   // c1 [128][72] bf16 (reuses SB0 after barrier)
    float* C2s  = (float*)(smem + 34816);   // c2 [128][33] f32 (reuses SB1 after barrier)
    short* FEAT = (short*)(smem + 53248);   // stat feats [128][40] bf16

    const int tid  = (int)threadIdx.x;
    const int lane = tid & 63;
    const int wave = tid >> 6;       // 0..7
    const int m    = lane & 31;      // MFMA row (A) / col (B,D)
    const int h    = lane >> 5;      // half: k-offset 8*h
    const int rowBase = (int)blockIdx.x * 128;

    // x octet assignment: thread t -> row t>>2, stored slot t&3, data octet xo (XOR swizzle)
    const int xr = tid >> 2;                  // 0..127
    const int xo = (tid & 3) ^ (xr & 3);      // octet (8 cols) within 32-col chunk
    const float* xrow = x + (size_t)(rowBase + xr) * 365;

    float s1 = 0.f, s2 = 0.f, s3 = 0.f, s4 = 0.f, mn = 1e30f, mx = -1e30f;
    unsigned sxd[48];        // stashed bf16 x (12 chunks x 4 dw)
    unsigned parkH1[64];     // h1 cols [32*wave] (pass A: 0..31) and [32*(8+wave)] (pass B: 32..63)
    unsigned park2[32];      // h2 cols [32*wave]
    unsigned park3[16];      // seq  rows 64*(wave&1).., cols 32*(wave>>1)..

    auto issue_x = [&](int c, float* xf) {
        #pragma unroll
        for (int j = 0; j < 8; ++j) {
            int col = c * 32 + xo * 8 + j;
            xf[j] = (col < 365) ? xrow[col] : 0.f;
        }
    };
    auto mom_stash = [&](int c, const float* xf) {
        #pragma unroll
        for (int q = 0; q < 4; ++q) sxd[c * 4 + q] = pk2(xf[2 * q], xf[2 * q + 1]);
        #pragma unroll
        for (int j = 0; j < 8; ++j) {
            int col = c * 32 + xo * 8 + j;
            if (col < 365) {
                float v = xf[j], v2 = v * v;
                s1 += v; s2 += v2; s3 += v2 * v; s4 += v2 * v2;
                mn = fminf(mn, v); mx = fmaxf(mx, v);
            }
        }
    };
    auto write_a = [&](int c, short* A) {     // contiguous lane-order write (addr16 == tid)
        int4 w4;
        w4.x = (int)sxd[c * 4 + 0]; w4.y = (int)sxd[c * 4 + 1];
        w4.z = (int)sxd[c * 4 + 2]; w4.w = (int)sxd[c * 4 + 3];
        *(int4*)(A + tid * 8) = w4;
    };
    auto ldA = [&](const short* A, int mt, int ks) -> short8 {   // swizzled A-frag read
        int a16 = (mt * 32 + m) * 4 + ((ks * 2 + h) ^ (m & 3));
        return *(const short8*)(A + a16 * 8);
    };
    auto ldS = [&](const short* S, int stride, int mt, int k0) -> short8 {
        return *(const short8*)(S + (mt * 32 + m) * stride + k0 + h * 8);
    };

    float16 A0, A1, A2, A3;
    #pragma unroll
    for (int i = 0; i < 16; ++i) { A0[i] = 0.f; A1[i] = 0.f; A2[i] = 0.f; A3[i] = 0.f; }
    float xfa[8], xfb[8];

    // ========== G1 pass A: h1 cols [32*wave, +32), fused x-load + stats ==========
    {
        const short* B1 = W1t + (wave * 32 + m) * 384 + h * 8;
        issue_x(0, xfa); issue_x(1, xfb);
        mom_stash(0, xfa);
        write_a(0, AB0);
        short8 bq0 = *(const short8*)(B1);
        short8 bq1 = *(const short8*)(B1 + 16);
        __syncthreads();
        #pragma unroll
        for (int c = 0; c < 12; ++c) {
            const short* Acur = (c & 1) ? AB1 : AB0;
            short*       Anxt = (c & 1) ? AB0 : AB1;
            if (c + 2 < 12) issue_x(c + 2, (c & 1) ? xfb : xfa);
            short8 nb0 = bq0, nb1 = bq1;
            if (c + 1 < 12) {
                nb0 = *(const short8*)(B1 + (c + 1) * 32);
                nb1 = *(const short8*)(B1 + (c + 1) * 32 + 16);
            }
            short8 a;
            a = ldA(Acur, 0, 0); A0 = mfma16(a, bq0, A0);
            a = ldA(Acur, 1, 0); A1 = mfma16(a, bq0, A1);
            a = ldA(Acur, 2, 0); A2 = mfma16(a, bq0, A2);
            a = ldA(Acur, 3, 0); A3 = mfma16(a, bq0, A3);
            a = ldA(Acur, 0, 1); A0 = mfma16(a, bq1, A0);
            a = ldA(Acur, 1, 1); A1 = mfma16(a, bq1, A1);
            a = ldA(Acur, 2, 1); A2 = mfma16(a, bq1, A2);
            a = ldA(Acur, 3, 1); A3 = mfma16(a, bq1, A3);
            if (c + 1 < 12) {
                mom_stash(c + 1, (c & 1) ? xfa : xfb);
                write_a(c + 1, Anxt);
            }
            bq0 = nb0; bq1 = nb1;
            __syncthreads();
        }
        float bb = b1f[wave * 32 + m];
        #pragma unroll
        for (int rr = 0; rr < 8; ++rr) {
            parkH1[rr]      = pk2(fmaxf(A0[2*rr] + bb, 0.f), fmaxf(A0[2*rr+1] + bb, 0.f));
            parkH1[8 + rr]  = pk2(fmaxf(A1[2*rr] + bb, 0.f), fmaxf(A1[2*rr+1] + bb, 0.f));
            parkH1[16 + rr] = pk2(fmaxf(A2[2*rr] + bb, 0.f), fmaxf(A2[2*rr+1] + bb, 0.f));
            parkH1[24 + rr] = pk2(fmaxf(A3[2*rr] + bb, 0.f), fmaxf(A3[2*rr+1] + bb, 0.f));
        }
    }

    // ========== stats finalize -> FEAT (quad reduce: 4 threads per row) ==========
    {
        #pragma unroll
        for (int off = 1; off <= 2; off <<= 1) {
            s1 += __shfl_xor(s1, off); s2 += __shfl_xor(s2, off);
            s3 += __shfl_xor(s3, off); s4 += __shfl_xor(s4, off);
            mn = fminf(mn, __shfl_xor(mn, off)); mx = fmaxf(mx, __shfl_xor(mx, off));
        }
        float mean  = s1 * (1.0f / 365.0f);
        float var1  = (s2 - 365.0f * mean * mean) * (1.0f / 364.0f);   // ddof=1
        float sigma = sqrtf(var1);
        float m3 = (s3 - 3.0f * mean * s2) * (1.0f / 365.0f) + 2.0f * mean * mean * mean;
        float mm = mean * mean;
        float m4 = (s4 - 4.0f * mean * s3 + 6.0f * mm * s2) * (1.0f / 365.0f) - 3.0f * mm * mm;
        float sg2 = sigma * sigma;
        float skew = m3 / (sigma * sg2 + 1e-8f);
        float kurt = m4 / (sg2 * sg2 + 1e-8f);
        float st[6] = { mean, sigma, mn, mx, skew, kurt };
        #pragma unroll
        for (int nn = 0; nn < 8; nn += 2) {
            int n0 = (tid & 3) * 8 + nn;
            float f0 = bsf[n0], f1 = bsf[n0 + 1];
            #pragma unroll
            for (int j = 0; j < 6; ++j) { f0 += st[j] * Wsf[j * 32 + n0]; f1 += st[j] * Wsf[j * 32 + n0 + 1]; }
            *(unsigned*)(FEAT + xr * 40 + n0) = pk2(f0, f1);
        }
    }

    // ========== G1 pass B: h1 cols [32*(8+wave), +32), staged from stash ==========
    {
        const short* B1 = W1t + ((8 + wave) * 32 + m) * 384 + h * 8;
        #pragma unroll
        for (int i = 0; i < 16; ++i) { A0[i] = 0.f; A1[i] = 0.f; A2[i] = 0.f; A3[i] = 0.f; }
        write_a(0, AB0);
        short8 bq0 = *(const short8*)(B1);
        short8 bq1 = *(const short8*)(B1 + 16);
        __syncthreads();
        #pragma unroll
        for (int c = 0; c < 12; ++c) {
            const short* Acur = (c & 1) ? AB1 : AB0;
            short*       Anxt = (c & 1) ? AB0 : AB1;
            short8 nb0 = bq0, nb1 = bq1;
            if (c + 1 < 12) {
                nb0 = *(const short8*)(B1 + (c + 1) * 32);
                nb1 = *(const short8*)(B1 + (c + 1) * 32 + 16);
            }
            short8 a;
            a = ldA(Acur, 0, 0); A0 = mfma16(a, bq0, A0);
            a = ldA(Acur, 1, 0); A1 = mfma16(a, bq0, A1);
            a = ldA(Acur, 2, 0); A2 = mfma16(a, bq0, A2);
            a = ldA(Acur, 3, 0); A3 = mfma16(a, bq0, A3);
            a = ldA(Acur, 0, 1); A0 = mfma16(a, bq1, A0);
            a = ldA(Acur, 1, 1); A1 = mfma16(a, bq1, A1);
            a = ldA(Acur, 2, 1); A2 = mfma16(a, bq1, A2);
            a = ldA(Acur, 3, 1); A3 = mfma16(a, bq1, A3);
            if (c + 1 < 12) write_a(c + 1, Anxt);
            bq0 = nb0; bq1 = nb1;
            __syncthreads();
        }
        float bb = b1f[(8 + wave) * 32 + m];
        #pragma unroll
        for (int rr = 0; rr < 8; ++rr) {
            parkH1[32 + rr]      = pk2(fmaxf(A0[2*rr] + bb, 0.f), fmaxf(A0[2*rr+1] + bb, 0.f));
            parkH1[32 + 8 + rr]  = pk2(fmaxf(A1[2*rr] + bb, 0.f), fmaxf(A1[2*rr+1] + bb, 0.f));
            parkH1[32 + 16 + rr] = pk2(fmaxf(A2[2*rr] + bb, 0.f), fmaxf(A2[2*rr+1] + bb, 0.f));
            parkH1[32 + 24 + rr] = pk2(fmaxf(A3[2*rr] + bb, 0.f), fmaxf(A3[2*rr+1] + bb, 0.f));
        }
    }

    // ========== G2: h2 = relu(h1 @ W2 + b2), K=512 in 8 chunks of 64 ==========
    float16 H0, H1, H2, H3;
    #pragma unroll
    for (int i = 0; i < 16; ++i) { H0[i] = 0.f; H1[i] = 0.f; H2[i] = 0.f; H3[i] = 0.f; }
    {
        const short* B2 = W2t + (wave * 32 + m) * 512 + h * 8;
        auto wS = [&](int c, short* S) {   // chunk c written by waves (2c)&7, +1
            int lo = (2 * c) & 7;
            int pb = (c < 4) ? 0 : 32;
            if (wave == lo || wave == lo + 1) {
                int col = (wave - lo) * 32 + m;
                #pragma unroll
                for (int mt = 0; mt < 4; ++mt)
                #pragma unroll
                for (int rr = 0; rr < 8; ++rr) {
                    unsigned pv = parkH1[pb + mt * 8 + rr];
                    S[(mt * 32 + rowof(2 * rr,     h)) * 72 + col] = (short)(pv & 0xffffu);
                    S[(mt * 32 + rowof(2 * rr + 1, h)) * 72 + col] = (short)(pv >> 16);
                }
            }
        };
        wS(0, SB0);
        short8 cb[4], nb[4];
        #pragma unroll
        for (int ks = 0; ks < 4; ++ks) cb[ks] = *(const short8*)(B2 + ks * 16);
        __syncthreads();
        #pragma unroll
        for (int c = 0; c < 8; ++c) {
            const short* Scur = (c & 1) ? SB1 : SB0;
            short*       Snxt = (c & 1) ? SB0 : SB1;
            if (c + 1 < 8) {
                wS(c + 1, Snxt);
                #pragma unroll
                for (int ks = 0; ks < 4; ++ks) nb[ks] = *(const short8*)(B2 + (c + 1) * 64 + ks * 16);
            }
            #pragma unroll
            for (int ks = 0; ks < 4; ++ks) {
                short8 a;
                a = ldS(Scur, 72, 0, ks * 16); H0 = mfma16(a, cb[ks], H0);
                a = ldS(Scur, 72, 1, ks * 16); H1 = mfma16(a, cb[ks], H1);
                a = ldS(Scur, 72, 2, ks * 16); H2 = mfma16(a, cb[ks], H2);
                a = ldS(Scur, 72, 3, ks * 16); H3 = mfma16(a, cb[ks], H3);
            }
            if (c + 1 < 8) {
                #pragma unroll
                for (int ks = 0; ks < 4; ++ks) cb[ks] = nb[ks];
            }
            __syncthreads();
        }
        float bb = b2f[wave * 32 + m];
        #pragma unroll
        for (int rr = 0; rr < 8; ++rr) {
            park2[rr]      = pk2(fmaxf(H0[2*rr] + bb, 0.f), fmaxf(H0[2*rr+1] + bb, 0.f));
            park2[8 + rr]  = pk2(fmaxf(H1[2*rr] + bb, 0.f), fmaxf(H1[2*rr+1] + bb, 0.f));
            park2[16 + rr] = pk2(fmaxf(H2[2*rr] + bb, 0.f), fmaxf(H2[2*rr+1] + bb, 0.f));
            park2[24 + rr] = pk2(fmaxf(H3[2*rr] + bb, 0.f), fmaxf(H3[2*rr+1] + bb, 0.f));
        }
    }

    // ========== G3: seq = relu(h2 @ W3 + b3), K=256 in 4 chunks ==========
    float16 Sq0, Sq1;
    #pragma unroll
    for (int i = 0; i < 16; ++i) { Sq0[i] = 0.f; Sq1[i] = 0.f; }
    {
        int nt3 = wave >> 1, mtb = 2 * (wave & 1);
        const short* B3 = W3t + (nt3 * 32 + m) * 256 + h * 8;
        auto wS3 = [&](int c, short* S) {   // chunk c written by waves 2c, 2c+1
            int lo = 2 * c;
            if (wave == lo || wave == lo + 1) {
                int col = (wave - lo) * 32 + m;
                #pragma unroll
                for (int mt = 0; mt < 4; ++mt)
                #pragma unroll
                for (int rr = 0; rr < 8; ++rr) {
                    unsigned pv = park2[mt * 8 + rr];
                    S[(mt * 32 + rowof(2 * rr,     h)) * 72 + col] = (short)(pv & 0xffffu);
                    S[(mt * 32 + rowof(2 * rr + 1, h)) * 72 + col] = (short)(pv >> 16);
                }
            }
        };
        wS3(0, SB0);
        short8 cb[4], nb[4];
        #pragma unroll
        for (int ks = 0; ks < 4; ++ks) cb[ks] = *(const short8*)(B3 + ks * 16);
        __syncthreads();
        #pragma unroll
        for (int c = 0; c < 4; ++c) {
            const short* Scur = (c & 1) ? SB1 : SB0;
            short*       Snxt = (c & 1) ? SB0 : SB1;
            if (c + 1 < 4) {
                wS3(c + 1, Snxt);
                #pragma unroll
                for (int ks = 0; ks < 4; ++ks) nb[ks] = *(const short8*)(B3 + (c + 1) * 64 + ks * 16);
            }
            #pragma unroll
            for (int ks = 0; ks < 4; ++ks) {
                short8 a;
                a = ldS(Scur, 72, mtb,     ks * 16); Sq0 = mfma16(a, cb[ks], Sq0);
                a = ldS(Scur, 72, mtb + 1, ks * 16); Sq1 = mfma16(a, cb[ks], Sq1);
            }
            if (c + 1 < 4) {
                #pragma unroll
                for (int ks = 0; ks < 4; ++ks) cb[ks] = nb[ks];
            }
            __syncthreads();
        }
        float bb = b3f[nt3 * 32 + m];
        #pragma unroll
        for (int rr = 0; rr < 8; ++rr) {
            park3[rr]     = pk2(fmaxf(Sq0[2*rr] + bb, 0.f), fmaxf(Sq0[2*rr+1] + bb, 0.f));
            park3[8 + rr] = pk2(fmaxf(Sq1[2*rr] + bb, 0.f), fmaxf(Sq1[2*rr+1] + bb, 0.f));
        }
    }

    // ========== G4: c1 = relu([seq|feat] @ Wc1 + bc1), K=160 (64+64+32) ==========
    {
        int mt4 = wave & 3, nt4 = wave >> 2;
        const short* B4 = Wc1t + (nt4 * 32 + m) * 160 + h * 8;
        float bb = bc1f[nt4 * 32 + m];
        float16 Cv;
        #pragma unroll
        for (int i = 0; i < 16; ++i) Cv[i] = 0.f;
        auto wS4 = [&](int c, short* S) {   // chunk c (0/1) written by waves 4c..4c+3
            if ((wave >> 2) == c) {
                int col = ((wave >> 1) & 1) * 32 + m;
                #pragma unroll
                for (int jj = 0; jj < 2; ++jj)
                #pragma unroll
                for (int rr = 0; rr < 8; ++rr) {
                    unsigned pv = park3[jj * 8 + rr];
                    int mt = 2 * (wave & 1) + jj;
                    S[(mt * 32 + rowof(2 * rr,     h)) * 72 + col] = (short)(pv & 0xffffu);
                    S[(mt * 32 + rowof(2 * rr + 1, h)) * 72 + col] = (short)(pv >> 16);
                }
            }
        };
        wS4(0, SB0); wS4(1, SB1);
        __syncthreads();
        #pragma unroll
        for (int ks = 0; ks < 4; ++ks) {
            short8 a = ldS(SB0, 72, mt4, ks * 16);
            short8 b = *(const short8*)(B4 + ks * 16);
            Cv = mfma16(a, b, Cv);
        }
        #pragma unroll
        for (int ks = 0; ks < 4; ++ks) {
            short8 a = ldS(SB1, 72, mt4, ks * 16);
            short8 b = *(const short8*)(B4 + 64 + ks * 16);
            Cv = mfma16(a, b, Cv);
        }
        #pragma unroll
        for (int ks = 0; ks < 2; ++ks) {
            short8 a = ldS(FEAT, 40, mt4, ks * 16);
            short8 b = *(const short8*)(B4 + 128 + ks * 16);
            Cv = mfma16(a, b, Cv);
        }
        __syncthreads();                     // all staging reads done before C1 overwrites SB0
        #pragma unroll
        for (int rr = 0; rr < 8; ++rr) {
            C1s[(mt4 * 32 + rowof(2 * rr,     h)) * 72 + nt4 * 32 + m] = f2bf(fmaxf(Cv[2*rr]   + bb, 0.f));
            C1s[(mt4 * 32 + rowof(2 * rr + 1, h)) * 72 + nt4 * 32 + m] = f2bf(fmaxf(Cv[2*rr+1] + bb, 0.f));
        }
        __syncthreads();
    }

    // ========== G5: c2 = relu(c1 @ Wc2 + bc2) -> C2 (fp32) ==========
    {
        if (wave < 4) {
            const short* B5 = Wc2t + m * 64 + h * 8;
            float bb = bc2f[m];
            float16 Cv;
            #pragma unroll
            for (int i = 0; i < 16; ++i) Cv[i] = 0.f;
            #pragma unroll
            for (int ks = 0; ks < 4; ++ks) {
                short8 a = ldS(C1s, 72, wave, ks * 16);
                short8 b = *(const short8*)(B5 + ks * 16);
                Cv = mfma16(a, b, Cv);
            }
            #pragma unroll
            for (int rr = 0; rr < 16; ++rr)
                C2s[(wave * 32 + rowof(rr, h)) * 33 + m] = fmaxf(Cv[rr] + bb, 0.f);
        }
        __syncthreads();
    }

    // ========== final: out = sigmoid(c2 . Wc3 + bc3) ==========
    if (tid < 128) {
        float z = bc3f[0];
        #pragma unroll
        for (int i = 0; i < 32; ++i) z += C2s[tid * 33 + i] * Wc3f[i];
        out[rowBase + tid] = 1.0f / (1.0f + expf(-z));
    }
}

extern "C" void kernel_launch(void* const* d_in, const int* in_sizes, int n_in,
                              void* d_out, int out_size, void* d_ws, size_t ws_size,
                              hipStream_t stream)
{
    (void)in_sizes; (void)n_in; (void)out_size; (void)ws_size;
    const float* x   = (const float*)d_in[0];
    const float* W1  = (const float*)d_in[1];
    const float* b1  = (const float*)d_in[2];
    const float* W2  = (const float*)d_in[3];
    const float* b2  = (const float*)d_in[4];
    const float* W3  = (const float*)d_in[5];
    const float* b3  = (const float*)d_in[6];
    const float* Ws  = (const float*)d_in[7];
    const float* bs  = (const float*)d_in[8];
    const float* Wc1 = (const float*)d_in[9];
    const float* bc1 = (const float*)d_in[10];
    const float* Wc2 = (const float*)d_in[11];
    const float* bc2 = (const float*)d_in[12];
    const float* Wc3 = (const float*)d_in[13];
    const float* bc3 = (const float*)d_in[14];
    short* ws = (short*)d_ws;

    prep_weights<<<1456, 256, 0, stream>>>(W1, W2, W3, Wc1, Wc2, ws);
    fused_mlp<<<512, 512, 0, stream>>>(x, b1, b2, b3, Ws, bs, bc1, bc2, Wc3, bc3,
                                       ws, ws + 196608, ws + 327680, ws + 360448, ws + 370688,
                                       (float*)d_out);
}

// Round 2
// 237.477 us; speedup vs baseline: 1.0031x; 1.0031x over previous
//
#include <hip/hip_runtime.h>
#include <math.h>

typedef __attribute__((ext_vector_type(8)))  short short8;   // 8 x bf16 (4 VGPR) MFMA operand
typedef __attribute__((ext_vector_type(16))) float float16;  // 32x32 MFMA accumulator

#define DEVI __device__ __forceinline__

DEVI short f2bf(float f) {                      // RNE float -> bf16 bits
    unsigned u = __float_as_uint(f);
    u = (u + 0x7fffu + ((u >> 16) & 1u)) >> 16;
    return (short)u;
}
DEVI unsigned pk2(float a, float b) {
    return (unsigned)(unsigned short)f2bf(a) | ((unsigned)(unsigned short)f2bf(b) << 16);
}
DEVI float16 mfma16(short8 a, short8 b, float16 c) {
    return __builtin_amdgcn_mfma_f32_32x32x16_bf16(a, b, c, 0, 0, 0);
}
// C/D row for reg r, half h: row = (r&3) + 8*(r>>2) + 4*h  [guide-verified, R1-passing]
DEVI int rowof(int r, int h) { return (r & 3) + 8 * (r >> 2) + 4 * h; }
DEVI short8 lds8(const short* p) { return *(const short8*)p; }

// ---- ws layout (shorts): MFMA-native [ceil(K/16)][N][16] bf16 ----
#define W1T_OFF  0          // [23][512][16] (K=365 pad 368)
#define W2T_OFF  188416     // [32][256][16]
#define W3T_OFF  319488     // [16][128][16]
#define WC1T_OFF 352256     // [10][64][16]
#define WC2T_OFF 362496     // [4][32][16]

// ---------------- prologue: coalesced transpose via LDS tiles ----------------
// block handles one (kc, 64-wide n-chunk) tile; reads coalesced (lane=n),
// writes coalesced 8B/lane in [kc][n][16] order.
__global__ void prep_v2(const float* __restrict__ W1, const float* __restrict__ W2,
                        const float* __restrict__ W3, const float* __restrict__ Wc1,
                        const float* __restrict__ Wc2, short* __restrict__ ws) {
    __shared__ short T[16 * 72];
    int b = blockIdx.x, t = threadIdx.x;
    const float* src; int K, N; size_t base; int kc, nb;
    if (b < 184)        {            src = W1;  K = 365; N = 512; base = W1T_OFF;  kc = b >> 3;  nb = b & 7; }
    else if (b < 312)   { int l = b - 184; src = W2;  K = 512; N = 256; base = W2T_OFF;  kc = l >> 2;  nb = l & 3; }
    else if (b < 344)   { int l = b - 312; src = W3;  K = 256; N = 128; base = W3T_OFF;  kc = l >> 1;  nb = l & 1; }
    else if (b < 354)   {            src = Wc1; K = 160; N = 64;  base = WC1T_OFF; kc = b - 344; nb = 0; }
    else                {            src = Wc2; K = 64;  N = 32;  base = WC2T_OFF; kc = b - 354; nb = 0; }
    int n = nb * 64 + (t & 63);
    int kr = t >> 6;
    #pragma unroll
    for (int i = 0; i < 4; ++i) {
        int krow = kr + 4 * i;                 // 0..15
        int k = kc * 16 + krow;
        float v = (k < K && n < N) ? src[(size_t)k * N + n] : 0.f;
        T[krow * 72 + (t & 63)] = f2bf(v);
    }
    __syncthreads();
    int n2 = t >> 2, ksq = (t & 3) * 4;
    int ng = nb * 64 + n2;
    if (ng < N) {
        unsigned lo = (unsigned)(unsigned short)T[ksq * 72 + n2]
                    | ((unsigned)(unsigned short)T[(ksq + 1) * 72 + n2] << 16);
        unsigned hi = (unsigned)(unsigned short)T[(ksq + 2) * 72 + n2]
                    | ((unsigned)(unsigned short)T[(ksq + 3) * 72 + n2] << 16);
        uint2 d; d.x = lo; d.y = hi;
        *(uint2*)(ws + base + ((size_t)kc * N + ng) * 16 + ksq) = d;
    }
}

// ---------------- fused main: BM=64, 1024 blocks x 512 threads ----------------
// x lives in LDS [64][376] bf16 (row stride 47x16B, odd -> conflict-free).
// G1 interleaved with G2 k-slabs: h1 never parked in regs (reg budget <=128).
__global__ __launch_bounds__(512, 4)
void fused_v2(const float* __restrict__ x,
              const float* __restrict__ b1f, const float* __restrict__ b2f,
              const float* __restrict__ b3f, const float* __restrict__ Wsf,
              const float* __restrict__ bsf, const float* __restrict__ bc1f,
              const float* __restrict__ bc2f, const float* __restrict__ Wc3f,
              const float* __restrict__ bc3f,
              const short* __restrict__ wsw, float* __restrict__ out)
{
    __shared__ __align__(16) char smem[65536];
    short* XT    = (short*)smem;               // [64][376] bf16 x-tile (48128 B)
    short* SB    = (short*)(smem + 48128);     // [64][136] staging (17408 B)
    short* C1    = (short*)smem;               // [64][72]  (aliases XT, x dead)
    short* FEATL = (short*)(smem + 12288);     // [64][40]  (aliases XT)
    float* C2    = (float*)(smem + 20480);     // [64][33]  f32 (aliases XT)

    const short* W1t  = wsw + W1T_OFF;
    const short* W2t  = wsw + W2T_OFF;
    const short* W3t  = wsw + W3T_OFF;
    const short* Wc1t = wsw + WC1T_OFF;
    const short* Wc2t = wsw + WC2T_OFF;

    const int tid  = (int)threadIdx.x;
    const int lane = tid & 63;
    const int wv   = tid >> 6;       // 0..7
    const int m    = lane & 31;
    const int h    = lane >> 5;
    const int mt   = wv & 1;         // row-tile: rows mt*32..+32
    const int nl   = wv >> 1;        // 0..3
    const int rowBase = (int)blockIdx.x * 64;

    // ---- fill XT + fused row moments (thread t: row t>>3, octets j,j+8,... ) ----
    const int r0 = tid >> 3, j0 = tid & 7;
    const float* xrow = x + (size_t)(rowBase + r0) * 365;
    float s1 = 0.f, s2 = 0.f, s3 = 0.f, s4 = 0.f, mn = 1e30f, mx = -1e30f;
    #pragma unroll
    for (int i = 0; i < 6; ++i) {
        int o = j0 + 8 * i;
        if (o <= 45) {                          // octets 0..45 used by MFMA (K=368)
            float xf[8];
            #pragma unroll
            for (int jj = 0; jj < 8; ++jj) {
                int col = o * 8 + jj;
                xf[jj] = (col < 365) ? xrow[col] : 0.f;
            }
            #pragma unroll
            for (int jj = 0; jj < 8; ++jj) {
                int col = o * 8 + jj;
                if (col < 365) {
                    float v = xf[jj], v2 = v * v;
                    s1 += v; s2 += v2; s3 += v2 * v; s4 += v2 * v2;
                    mn = fminf(mn, v); mx = fmaxf(mx, v);
                }
            }
            int4 w4;
            w4.x = (int)pk2(xf[0], xf[1]); w4.y = (int)pk2(xf[2], xf[3]);
            w4.z = (int)pk2(xf[4], xf[5]); w4.w = (int)pk2(xf[6], xf[7]);
            *(int4*)(XT + r0 * 376 + o * 8) = w4;
        }
    }
    // reduce moments across the 8 lanes sharing a row (consecutive tids)
    #pragma unroll
    for (int off = 1; off <= 4; off <<= 1) {
        s1 += __shfl_xor(s1, off); s2 += __shfl_xor(s2, off);
        s3 += __shfl_xor(s3, off); s4 += __shfl_xor(s4, off);
        mn = fminf(mn, __shfl_xor(mn, off)); mx = fmaxf(mx, __shfl_xor(mx, off));
    }
    unsigned fdw0, fdw1;                        // parked feat (4 cols/thread)
    {
        float mean  = s1 * (1.0f / 365.0f);
        float var1  = (s2 - 365.0f * mean * mean) * (1.0f / 364.0f);
        float sigma = sqrtf(var1);
        float m3 = (s3 - 3.0f * mean * s2) * (1.0f / 365.0f) + 2.0f * mean * mean * mean;
        float mm = mean * mean;
        float m4 = (s4 - 4.0f * mean * s3 + 6.0f * mm * s2) * (1.0f / 365.0f) - 3.0f * mm * mm;
        float sg2 = sigma * sigma;
        float skew = m3 / (sigma * sg2 + 1e-8f);
        float kurt = m4 / (sg2 * sg2 + 1e-8f);
        float st[6] = { mean, sigma, mn, mx, skew, kurt };
        float f[4];
        #pragma unroll
        for (int c0 = 0; c0 < 4; ++c0) {
            int c = 4 * j0 + c0;
            float acc = bsf[c];
            #pragma unroll
            for (int jj = 0; jj < 6; ++jj) acc += st[jj] * Wsf[jj * 32 + c];
            f[c0] = acc;
        }
        fdw0 = pk2(f[0], f[1]); fdw1 = pk2(f[2], f[3]);
    }
    __syncthreads();                            // XT ready

    // ---- G1 (x @ W1, K=368) interleaved with G2 (h1 @ W2) k-slabs ----
    float16 h2a0, h2a1;
    #pragma unroll
    for (int i = 0; i < 16; ++i) { h2a0[i] = 0.f; h2a1[i] = 0.f; }

    const short* Ap = XT + (mt * 32 + m) * 376 + h * 8;

    for (int p = 0; p < 2; ++p) {
        float16 ga0, ga1;
        #pragma unroll
        for (int i = 0; i < 16; ++i) { ga0[i] = 0.f; ga1[i] = 0.f; }
        int nc0 = 256 * p + 32 * nl;
        const short* Bp0 = W1t + (nc0 + m) * 16 + h * 8;
        const short* Bp1 = Bp0 + 128 * 16;
        #pragma unroll
        for (int kc = 0; kc < 23; ++kc) {       // one A-read feeds 2 MFMAs
            short8 a  = lds8(Ap + kc * 16);
            short8 b0 = *(const short8*)(Bp0 + kc * 8192);
            short8 b1 = *(const short8*)(Bp1 + kc * 8192);
            ga0 = mfma16(a, b0, ga0);
            ga1 = mfma16(a, b1, ga1);
        }
        #pragma unroll
        for (int q = 0; q < 2; ++q) {
            __syncthreads();                    // prior SB consumers done
            {
                int nc = 256 * p + 128 * q + 32 * nl;
                float bb = b1f[nc + m];
                float16 A;
                if (q) A = ga1; else A = ga0;
                #pragma unroll
                for (int r = 0; r < 16; ++r) {
                    int rw = mt * 32 + rowof(r, h);
                    SB[rw * 136 + 32 * nl + m] = f2bf(fmaxf(A[r] + bb, 0.f));
                }
            }
            __syncthreads();                    // slab staged
            int slab = 2 * p + q;
            const short* A2p  = SB + (mt * 32 + m) * 136 + h * 8;
            const short* B2p0 = W2t + (size_t)slab * 8 * 4096 + (32 * nl + m) * 16 + h * 8;
            const short* B2p1 = B2p0 + 128 * 16;
            #pragma unroll
            for (int i = 0; i < 8; ++i) {
                short8 a  = lds8(A2p + i * 16);
                short8 b0 = *(const short8*)(B2p0 + i * 4096);
                short8 b1 = *(const short8*)(B2p1 + i * 4096);
                h2a0 = mfma16(a, b0, h2a0);
                h2a1 = mfma16(a, b1, h2a1);
            }
        }
    }

    // ---- G3: seq = relu(h2 @ W3 + b3), K=256 as 2 slabs of 128 ----
    float16 g3a;
    #pragma unroll
    for (int i = 0; i < 16; ++i) g3a[i] = 0.f;
    for (int s = 0; s < 2; ++s) {
        __syncthreads();
        {
            float bb = b2f[32 * nl + 128 * s + m];
            float16 A;
            if (s) A = h2a1; else A = h2a0;
            #pragma unroll
            for (int r = 0; r < 16; ++r) {
                int rw = mt * 32 + rowof(r, h);
                SB[rw * 136 + 32 * nl + m] = f2bf(fmaxf(A[r] + bb, 0.f));
            }
        }
        __syncthreads();
        const short* A3p = SB + (mt * 32 + m) * 136 + h * 8;
        const short* B3p = W3t + (size_t)s * 8 * 2048 + (32 * nl + m) * 16 + h * 8;
        #pragma unroll
        for (int i = 0; i < 8; ++i) {
            short8 a = lds8(A3p + i * 16);
            short8 b = *(const short8*)(B3p + i * 2048);
            g3a = mfma16(a, b, g3a);
        }
    }

    // ---- G4 stage: seq -> SB (full 128 cols), feat -> FEATL ----
    __syncthreads();
    {
        float bb = b3f[32 * nl + m];
        #pragma unroll
        for (int r = 0; r < 16; ++r) {
            int rw = mt * 32 + rowof(r, h);
            SB[rw * 136 + 32 * nl + m] = f2bf(fmaxf(g3a[r] + bb, 0.f));
        }
        *(unsigned*)(FEATL + r0 * 40 + 4 * j0)     = fdw0;
        *(unsigned*)(FEATL + r0 * 40 + 4 * j0 + 2) = fdw1;
    }
    __syncthreads();

    // ---- G4: c1 = relu([seq|feat] @ Wc1 + bc1), K=160, waves 0..3 ----
    if (wv < 4) {
        int nt4 = wv >> 1;
        float16 g4a;
        #pragma unroll
        for (int i = 0; i < 16; ++i) g4a[i] = 0.f;
        const short* A4p = SB + (mt * 32 + m) * 136 + h * 8;
        const short* B4p = Wc1t + (32 * nt4 + m) * 16 + h * 8;
        #pragma unroll
        for (int i = 0; i < 8; ++i) {
            short8 a = lds8(A4p + i * 16);
            short8 b = *(const short8*)(B4p + i * 1024);
            g4a = mfma16(a, b, g4a);
        }
        const short* AF = FEATL + (mt * 32 + m) * 40 + h * 8;
        #pragma unroll
        for (int i = 0; i < 2; ++i) {
            short8 a = lds8(AF + i * 16);
            short8 b = *(const short8*)(B4p + (8 + i) * 1024);
            g4a = mfma16(a, b, g4a);
        }
        float bb = bc1f[32 * nt4 + m];
        #pragma unroll
        for (int r = 0; r < 16; ++r) {
            int rw = mt * 32 + rowof(r, h);
            C1[rw * 72 + 32 * nt4 + m] = f2bf(fmaxf(g4a[r] + bb, 0.f));
        }
    }
    __syncthreads();

    // ---- G5: c2 = relu(c1 @ Wc2 + bc2) -> C2 f32, waves 0..1 ----
    if (wv < 2) {
        float16 g5;
        #pragma unroll
        for (int i = 0; i < 16; ++i) g5[i] = 0.f;
        const short* A5p = C1 + (wv * 32 + m) * 72 + h * 8;
        const short* B5p = Wc2t + m * 16 + h * 8;
        #pragma unroll
        for (int i = 0; i < 4; ++i) {
            short8 a = lds8(A5p + i * 16);
            short8 b = *(const short8*)(B5p + i * 512);
            g5 = mfma16(a, b, g5);
        }
        float bb = bc2f[m];
        #pragma unroll
        for (int r = 0; r < 16; ++r) {
            int rw = wv * 32 + rowof(r, h);
            C2[rw * 33 + m] = fmaxf(g5[r] + bb, 0.f);
        }
    }
    __syncthreads();

    // ---- final: out = sigmoid(c2 . Wc3 + bc3) ----
    if (tid < 64) {
        float z = bc3f[0];
        #pragma unroll
        for (int i = 0; i < 32; ++i) z += C2[tid * 33 + i] * Wc3f[i];
        out[rowBase + tid] = 1.0f / (1.0f + expf(-z));
    }
}

extern "C" void kernel_launch(void* const* d_in, const int* in_sizes, int n_in,
                              void* d_out, int out_size, void* d_ws, size_t ws_size,
                              hipStream_t stream)
{
    (void)in_sizes; (void)n_in; (void)out_size; (void)ws_size;
    const float* x   = (const float*)d_in[0];
    const float* W1  = (const float*)d_in[1];
    const float* b1  = (const float*)d_in[2];
    const float* W2  = (const float*)d_in[3];
    const float* b2  = (const float*)d_in[4];
    const float* W3  = (const float*)d_in[5];
    const float* b3  = (const float*)d_in[6];
    const float* Ws  = (const float*)d_in[7];
    const float* bs  = (const float*)d_in[8];
    const float* Wc1 = (const float*)d_in[9];
    const float* bc1 = (const float*)d_in[10];
    const float* Wc2 = (const float*)d_in[11];
    const float* bc2 = (const float*)d_in[12];
    const float* Wc3 = (const float*)d_in[13];
    const float* bc3 = (const float*)d_in[14];
    short* ws = (short*)d_ws;

    prep_v2<<<358, 256, 0, stream>>>(W1, W2, W3, Wc1, Wc2, ws);
    fused_v2<<<1024, 512, 0, stream>>>(x, b1, b2, b3, Ws, bs, bc1, bc2, Wc3, bc3,
                                       ws, (float*)d_out);
}